// Round 4
// baseline (24.018 us; speedup 1.0000x reference)
//
#include <hip/hip_runtime.h>

// upsample_nn: values [C=64, N=4096] f32, coords [N,2] f32 in [0,1)
// out [C, 4N]: first N cols = values, next 3N cols = values[:, argmin_j d2(g,j)]
//
// Reference d2 semantics (verified bit-exact in R3, contraction OFF):
//   qx = (x [+0.001f]) - 0.0005f   (f32, per variant)
//   qq = qx*qx + qy*qy ; cc = cx*cx + cy*cy          (plain mul/add)
//   qc = fmaf(qy, cy, qx*cx)                          (K=2 FMA dot)
//   d2 = (qq + cc) - (qc + qc)
//   argmin = first occurrence  -> lexicographic (d2, idx) min (order-free)
//
// Work reduction (provable): winner w obeys computed_d2(w) <= computed_d2(src).
// |computed-exact| <= delta (=3e-6, conservative; true bound ~1.4e-6), and
// exact_d2(src) <= 2*(5.01e-4)^2 = 5.02e-7, so exact_d2(w) <= 6.5e-6
// -> |dx|,|dy| <= 2.55e-3 < R = 3.5e-3. A 64x64 grid (cell 1/64) searched
// over the [q-R, q+R] box (<= 2x2 cells, floor is monotone, ~1e-3 margin
// swamps fp rounding of the cell index) contains every possible winner/tie.

#pragma clang fp contract(off)

constexpr int   Nn    = 4096;
constexpr int   Cc    = 64;
constexpr int   NQ    = 3 * Nn;          // 12288
constexpr int   GD    = 64;              // grid dim
constexpr int   NCELL = GD * GD;         // 4096 cells, lambda = 1 pt/cell
constexpr int   CAP   = 16;              // per-cell capacity (P(overflow)~1e-13)
constexpr int   OVCAP = Nn;              // overflow list can hold everything
constexpr float Rm    = 3.5e-3f;

// ws layout (ints): [0,NCELL)=cnt | [NCELL]=ovCnt | [NCELL+1,+OVCAP)=ov |
//                   then cellList[NCELL][CAP].  Total ~295 KB.
constexpr int WS_OVCNT = NCELL;
constexpr int WS_OV    = NCELL + 1;
constexpr int WS_LIST  = NCELL + 1 + OVCAP;

__global__ __launch_bounds__(256) void zero_grid_kernel(int* __restrict__ ws) {
    for (int i = blockIdx.x * 256 + threadIdx.x; i < NCELL + 1; i += 8 * 256)
        ws[i] = 0;
}

__global__ __launch_bounds__(256) void build_grid_kernel(
    const float* __restrict__ coords, int* __restrict__ ws) {
    int j = blockIdx.x * 256 + threadIdx.x;          // 16 blocks x 256 = 4096
    float2 c = reinterpret_cast<const float2*>(coords)[j];
    int cx = min(GD - 1, (int)(c.x * (float)GD));    // c in [0,1): trunc=floor
    int cy = min(GD - 1, (int)(c.y * (float)GD));
    int cell = cy * GD + cx;
    int pos = atomicAdd(&ws[cell], 1);
    if (pos < CAP) {
        ws[WS_LIST + cell * CAP + pos] = j;
    } else {
        int o = atomicAdd(&ws[WS_OVCNT], 1);
        if (o < OVCAP) ws[WS_OV + o] = j;            // always true (<= Nn)
    }
}

// blocks [0,48): 256 queries each (resolve argmin + write 64 channels)
// blocks [48,112): float4 copy of values -> out[:, 0:Nn]
__global__ __launch_bounds__(256) void query_kernel(
    const float* __restrict__ values,   // [Cc][Nn]
    const float* __restrict__ coords,   // [Nn][2]
    const int*   __restrict__ ws,
    float* __restrict__ out)            // [Cc][4*Nn]
{
#pragma clang fp contract(off)
    const int tid = threadIdx.x;

    if (blockIdx.x >= 48) {             // ---- values copy, 1 MB as float4 ----
        int b = blockIdx.x - 48;        // 0..63
        #pragma unroll
        for (int k = 0; k < 4; ++k) {
            int gi  = b * 1024 + k * 256 + tid;      // 65536 float4 total
            int row = gi >> 10;                      // values row (1024 f4/row)
            int c4  = gi & 1023;
            float4 v = reinterpret_cast<const float4*>(values)[row * 1024 + c4];
            reinterpret_cast<float4*>(out)[row * 4096 + c4] = v; // out: 4096 f4/row
        }
        return;
    }

    // ---- one query per thread ----
    const int q   = blockIdx.x * 256 + tid;          // [0, 12288)
    const int i   = q & (Nn - 1);                    // source point
    const int var = q >> 12;                         // variant 0/1/2

    float2 ci = reinterpret_cast<const float2*>(coords)[i];
    const float x = ci.x, y = ci.y;
    float qx, qy;
    if (var == 0) {                                  // (x, y+sy) - shift
        qx = x - 0.0005f;
        qy = (y + 0.001f) - 0.0005f;
    } else if (var == 1) {                           // (x+sx, y) - shift
        qx = (x + 0.001f) - 0.0005f;
        qy = y - 0.0005f;
    } else {                                         // (x+sx, y+sy) - shift
        qx = (x + 0.001f) - 0.0005f;
        qy = (y + 0.001f) - 0.0005f;
    }
    const float qq = qx * qx + qy * qy;              // contract(off): plain

    int xlo = max(0, (int)floorf((qx - Rm) * (float)GD));
    int xhi = min(GD - 1, (int)floorf((qx + Rm) * (float)GD));
    int ylo = max(0, (int)floorf((qy - Rm) * (float)GD));
    int yhi = min(GD - 1, (int)floorf((qy + Rm) * (float)GD));

    float bd = INFINITY;
    int   bi = 0x7fffffff;

#define EVAL(JJ)                                                              \
    {                                                                         \
        int    jj = (JJ);                                                     \
        float2 c  = reinterpret_cast<const float2*>(coords)[jj];              \
        float  cc = c.x * c.x + c.y * c.y;                                    \
        float  qc = __builtin_fmaf(qy, c.y, qx * c.x);                        \
        float  d2 = (qq + cc) - (qc + qc);                                    \
        if (d2 < bd || (d2 == bd && jj < bi)) { bd = d2; bi = jj; }           \
    }

    for (int cy = ylo; cy <= yhi; ++cy)
        for (int cx = xlo; cx <= xhi; ++cx) {
            int cell = cy * GD + cx;
            int n = min(ws[cell], CAP);
            for (int k = 0; k < n; ++k)
                EVAL(ws[WS_LIST + cell * CAP + k]);
        }
    {   // overflow list (normally empty)
        int ovn = min(ws[WS_OVCNT], OVCAP);
        for (int k = 0; k < ovn; ++k)
            EVAL(ws[WS_OV + k]);
    }
#undef EVAL

    // ---- write out[ch, Nn + q] for all 64 channels (coalesced across tid) ----
    #pragma unroll 4
    for (int ch = 0; ch < Cc; ++ch)
        out[(size_t)ch * (4 * Nn) + Nn + q] = values[ch * Nn + bi];
}

extern "C" void kernel_launch(void* const* d_in, const int* in_sizes, int n_in,
                              void* d_out, int out_size, void* d_ws, size_t ws_size,
                              hipStream_t stream) {
    const float* values = (const float*)d_in[0];  // [64, 4096] f32
    const float* coords = (const float*)d_in[1];  // [4096, 2] f32
    float* out = (float*)d_out;                   // [64, 16384] f32
    int* ws = (int*)d_ws;                         // ~295 KB used

    hipLaunchKernelGGL(zero_grid_kernel,  dim3(8),   dim3(256), 0, stream, ws);
    hipLaunchKernelGGL(build_grid_kernel, dim3(16),  dim3(256), 0, stream, coords, ws);
    hipLaunchKernelGGL(query_kernel,      dim3(112), dim3(256), 0, stream,
                       values, coords, ws, out);
}

// Round 5
// 15.432 us; speedup vs baseline: 1.5563x; 1.5563x over previous
//
#include <hip/hip_runtime.h>

// upsample_nn: values [C=64, N=4096] f32, coords [N,2] f32 in [0,1)
// out [C, 4N]: first N cols = values, next 3N cols = values[:, argmin_j d2(g,j)]
//
// Reference d2 semantics (verified bit-exact in R3/R4, contraction OFF):
//   qx = (x [+0.001f]) - 0.0005f   (f32, per variant)
//   qq = qx*qx + qy*qy ; cc = cx*cx + cy*cy          (plain mul/add)
//   qc = fmaf(qy, cy, qx*cx)                          (K=2 FMA dot)
//   d2 = (qq + cc) - (qc + qc)
//   argmin = first occurrence -> lexicographic (d2, idx) min (order-free)
//
// Window proof (R4, unchanged): any candidate that can win/tie has exact
// distance <= 2.55e-3 < R = 3.5e-3; a 64x64 grid searched over [q-R, q+R]
// (<= 2x2 cells; floor monotone; ~1e-3 slack >> fp rounding) contains all
// possible winners.
//
// SINGLE LAUNCH (R4 lesson: 3 launches cost ~6 us of overhead): each query
// block counting-sorts all 4096 points into a per-block LDS cell grid
// (coords 32KB + counts 16KB + sorted ushort 8KB = 56KB), then resolves
// 256 queries against <=2 contiguous cell ranges. Copy blocks ride along.

#pragma clang fp contract(off)

constexpr int   Nn    = 4096;
constexpr int   Cc    = 64;
constexpr int   NQ    = 3 * Nn;          // 12288
constexpr int   GD    = 64;              // cell grid dim (cell = 1/64)
constexpr int   NCELL = GD * GD;         // 4096
constexpr float Rm    = 3.5e-3f;
constexpr int   QBLK  = NQ / 256;        // 48 query blocks
constexpr int   NBLK  = QBLK + 64;       // + 64 copy blocks

__global__ __launch_bounds__(256) void upsample_fused_kernel(
    const float* __restrict__ values,   // [Cc][Nn]
    const float* __restrict__ coords,   // [Nn][2]
    float* __restrict__ out)            // [Cc][4*Nn]
{
#pragma clang fp contract(off)
    __shared__ float2         sC[Nn];     // 32 KB candidate coords
    __shared__ int            sCnt[NCELL];// 16 KB counts -> starts -> end cursors
    __shared__ unsigned short sSort[Nn];  // 8 KB point ids, cell-sorted
    __shared__ int            sWave[4];   // wave scan partials

    const int tid = threadIdx.x;

    // ---------------- copy blocks: values -> out[:, 0:Nn] ----------------
    if (blockIdx.x >= QBLK) {
        int b = blockIdx.x - QBLK;        // 0..63 ; 65536 float4 total
        #pragma unroll
        for (int k = 0; k < 4; ++k) {
            int gi  = b * 1024 + k * 256 + tid;
            int row = gi >> 10;           // values: 1024 float4 per row
            int c4  = gi & 1023;
            float4 v = reinterpret_cast<const float4*>(values)[row * 1024 + c4];
            reinterpret_cast<float4*>(out)[row * 4096 + c4] = v; // out: 4096 f4/row
        }
        return;
    }

    // ---------------- phase 0: zero counts + stage coords ----------------
    #pragma unroll
    for (int k = 0; k < NCELL / 256; ++k) sCnt[tid + 256 * k] = 0;
    #pragma unroll
    for (int k = 0; k < Nn / 256; ++k) {
        int j = tid + 256 * k;
        sC[j] = reinterpret_cast<const float2*>(coords)[j];
    }
    __syncthreads();

    // ---------------- phase 1: bin (LDS atomics) ----------------
    #pragma unroll
    for (int k = 0; k < Nn / 256; ++k) {
        int j = tid + 256 * k;
        float2 c = sC[j];
        int cx = min(GD - 1, (int)(c.x * (float)GD));  // c in [0,1): trunc=floor
        int cy = min(GD - 1, (int)(c.y * (float)GD));
        atomicAdd(&sCnt[cy * GD + cx], 1);
    }
    __syncthreads();

    // ---------------- phase 2: exclusive scan of 4096 counts ----------------
    // thread owns cells [16*tid, 16*tid+16)
    int loc[16];
    int run = 0;
    #pragma unroll
    for (int k = 0; k < 16; ++k) { loc[k] = run; run += sCnt[tid * 16 + k]; }
    const int lane = tid & 63, wid = tid >> 6;
    int inc = run;
    #pragma unroll
    for (int off = 1; off < 64; off <<= 1) {
        int nv = __shfl_up(inc, off, 64);
        if (lane >= off) inc += nv;
    }
    if (lane == 63) sWave[wid] = inc;
    __syncthreads();
    int woff = 0;
    #pragma unroll
    for (int w = 0; w < 4; ++w) if (w < wid) woff += sWave[w];
    const int texcl = woff + (inc - run);   // exclusive start of this thread's cells
    __syncthreads();                        // sWave consumed; cell regions disjoint
    #pragma unroll
    for (int k = 0; k < 16; ++k) sCnt[tid * 16 + k] = texcl + loc[k];
    __syncthreads();

    // ---------------- phase 3: scatter (counting sort) ----------------
    #pragma unroll
    for (int k = 0; k < Nn / 256; ++k) {
        int j = tid + 256 * k;
        float2 c = sC[j];
        int cx = min(GD - 1, (int)(c.x * (float)GD));
        int cy = min(GD - 1, (int)(c.y * (float)GD));
        int pos = atomicAdd(&sCnt[cy * GD + cx], 1);
        sSort[pos] = (unsigned short)j;
    }
    __syncthreads();
    // now sCnt[cell] = end cursor; start(cell) = (cell==0 ? 0 : sCnt[cell-1])

    // ---------------- phase 4: one query per thread ----------------
    const int q   = blockIdx.x * 256 + tid;   // [0, 12288)
    const int i   = q & (Nn - 1);             // source point
    const int var = q >> 12;                  // variant 0/1/2

    float2 ci = sC[i];
    const float x = ci.x, y = ci.y;
    float qx, qy;
    if (var == 0) {                           // (x, y+sy) - shift
        qx = x - 0.0005f;
        qy = (y + 0.001f) - 0.0005f;
    } else if (var == 1) {                    // (x+sx, y) - shift
        qx = (x + 0.001f) - 0.0005f;
        qy = y - 0.0005f;
    } else {                                  // (x+sx, y+sy) - shift
        qx = (x + 0.001f) - 0.0005f;
        qy = (y + 0.001f) - 0.0005f;
    }
    const float qq = qx * qx + qy * qy;       // contract(off): plain

    const int xlo = max(0, (int)floorf((qx - Rm) * (float)GD));
    const int xhi = min(GD - 1, (int)floorf((qx + Rm) * (float)GD));
    const int ylo = max(0, (int)floorf((qy - Rm) * (float)GD));
    const int yhi = min(GD - 1, (int)floorf((qy + Rm) * (float)GD));

    float bd = INFINITY;
    int   bi = 0x7fffffff;
    for (int cy = ylo; cy <= yhi; ++cy) {
        int cellLo = cy * GD + xlo;
        int cellHi = cy * GD + xhi;
        int s = (cellLo == 0) ? 0 : sCnt[cellLo - 1];
        int e = sCnt[cellHi];                 // contiguous range across the row
        for (int p = s; p < e; ++p) {
            int    jj = sSort[p];
            float2 c  = sC[jj];
            float  cc = c.x * c.x + c.y * c.y;
            float  qc = __builtin_fmaf(qy, c.y, qx * c.x);
            float  d2 = (qq + cc) - (qc + qc);
            if (d2 < bd || (d2 == bd && jj < bi)) { bd = d2; bi = jj; }
        }
    }

    // ---------------- phase 5: write 64 channels ----------------
    #pragma unroll 4
    for (int ch = 0; ch < Cc; ++ch)
        out[(size_t)ch * (4 * Nn) + Nn + q] = values[ch * Nn + bi];
}

extern "C" void kernel_launch(void* const* d_in, const int* in_sizes, int n_in,
                              void* d_out, int out_size, void* d_ws, size_t ws_size,
                              hipStream_t stream) {
    const float* values = (const float*)d_in[0];  // [64, 4096] f32
    const float* coords = (const float*)d_in[1];  // [4096, 2] f32
    float* out = (float*)d_out;                   // [64, 16384] f32
    hipLaunchKernelGGL(upsample_fused_kernel, dim3(NBLK), dim3(256), 0, stream,
                       values, coords, out);
}

// Round 6
// 13.240 us; speedup vs baseline: 1.8140x; 1.1656x over previous
//
#include <hip/hip_runtime.h>

// upsample_nn: values [C=64, N=4096] f32, coords [N,2] f32 in [0,1)
// out [C, 4N]: first N cols = values, next 3N cols = values[:, argmin_j d2(g,j)]
//
// Reference d2 semantics (verified bit-exact R3/R4/R5, contraction OFF):
//   qx = (x [+0.001f]) - 0.0005f   (f32, per variant)
//   qq = qx*qx + qy*qy ; cc = cx*cx + cy*cy          (plain mul/add)
//   qc = fmaf(qy, cy, qx*cx)                          (K=2 FMA dot)
//   d2 = (qq + cc) - (qc + qc)
//   argmin = first occurrence -> lexicographic (d2, idx) min (order-free)
//
// Window proof (R4, unchanged): any winner/tie has exact distance <= 2.55e-3
// < R = 3.5e-3; 64x64 grid searched over [q-R, q+R] (<=2x2 cells, floor
// monotone, ~1e-3 slack >> fp rounding) contains all possible winners.
//
// R5 lesson: build is wall-time-constant in #blocks (each block builds its
// own LDS grid in parallel); query+gather scale with #blocks. So spread the
// 12288 queries over 192 blocks (64 q/block) + 64 copy blocks = 256 blocks
// (~1 per CU), cutting the per-block gather/query tail ~4x.

#pragma clang fp contract(off)

constexpr int   Nn    = 4096;
constexpr int   Cc    = 64;
constexpr int   NQ    = 3 * Nn;          // 12288
constexpr int   GD    = 64;              // cell grid dim (cell = 1/64)
constexpr int   NCELL = GD * GD;         // 4096
constexpr float Rm    = 3.5e-3f;
constexpr int   QPB   = 64;              // queries per block
constexpr int   QBLK  = NQ / QPB;        // 192 query blocks
constexpr int   NBLK  = QBLK + 64;       // + 64 copy blocks = 256

__global__ __launch_bounds__(256) void upsample_fused_kernel(
    const float* __restrict__ values,   // [Cc][Nn]
    const float* __restrict__ coords,   // [Nn][2]
    float* __restrict__ out)            // [Cc][4*Nn]
{
#pragma clang fp contract(off)
    __shared__ float2         sC[Nn];      // 32 KB candidate coords
    __shared__ int            sCnt[NCELL]; // 16 KB counts -> starts -> cursors
    __shared__ unsigned short sSort[Nn];   // 8 KB point ids, cell-sorted
    __shared__ int            sWave[4];    // scan partials
    __shared__ int            sBi[QPB];    // resolved argmin per query

    const int tid = threadIdx.x;

    // ---------------- copy blocks: values -> out[:, 0:Nn] ----------------
    if (blockIdx.x >= QBLK) {
        int b = blockIdx.x - QBLK;         // 0..63 ; 65536 float4 total
        #pragma unroll
        for (int k = 0; k < 4; ++k) {
            int gi  = b * 1024 + k * 256 + tid;
            int row = gi >> 10;            // values: 1024 float4 per row
            int c4  = gi & 1023;
            float4 v = reinterpret_cast<const float4*>(values)[row * 1024 + c4];
            reinterpret_cast<float4*>(out)[row * 4096 + c4] = v; // 4096 f4/row
        }
        return;
    }

    // ---------------- phase 0: zero counts + stage coords ----------------
    #pragma unroll
    for (int k = 0; k < NCELL / 256; ++k) sCnt[tid + 256 * k] = 0;
    #pragma unroll
    for (int k = 0; k < Nn / 256; ++k) {
        int j = tid + 256 * k;
        sC[j] = reinterpret_cast<const float2*>(coords)[j];
    }
    __syncthreads();

    // ---------------- phase 1: bin (LDS atomics) ----------------
    #pragma unroll
    for (int k = 0; k < Nn / 256; ++k) {
        int j = tid + 256 * k;
        float2 c = sC[j];
        int cx = min(GD - 1, (int)(c.x * (float)GD));  // [0,1): trunc=floor
        int cy = min(GD - 1, (int)(c.y * (float)GD));
        atomicAdd(&sCnt[cy * GD + cx], 1);
    }
    __syncthreads();

    // ---------------- phase 2: exclusive scan of 4096 counts ----------------
    int loc[16];
    int run = 0;
    #pragma unroll
    for (int k = 0; k < 16; ++k) { loc[k] = run; run += sCnt[tid * 16 + k]; }
    const int lane = tid & 63, wid = tid >> 6;
    int inc = run;
    #pragma unroll
    for (int off = 1; off < 64; off <<= 1) {
        int nv = __shfl_up(inc, off, 64);
        if (lane >= off) inc += nv;
    }
    if (lane == 63) sWave[wid] = inc;
    __syncthreads();
    int woff = 0;
    #pragma unroll
    for (int w = 0; w < 4; ++w) if (w < wid) woff += sWave[w];
    const int texcl = woff + (inc - run);
    __syncthreads();
    #pragma unroll
    for (int k = 0; k < 16; ++k) sCnt[tid * 16 + k] = texcl + loc[k];
    __syncthreads();

    // ---------------- phase 3: scatter (counting sort) ----------------
    #pragma unroll
    for (int k = 0; k < Nn / 256; ++k) {
        int j = tid + 256 * k;
        float2 c = sC[j];
        int cx = min(GD - 1, (int)(c.x * (float)GD));
        int cy = min(GD - 1, (int)(c.y * (float)GD));
        int pos = atomicAdd(&sCnt[cy * GD + cx], 1);
        sSort[pos] = (unsigned short)j;
    }
    __syncthreads();
    // sCnt[cell] = end cursor; start(cell) = (cell==0 ? 0 : sCnt[cell-1])

    // ---------------- phase 4: 64 queries, one per lane of wave 0 ----------
    if (tid < QPB) {
        const int q   = blockIdx.x * QPB + tid;   // [0, 12288)
        const int i   = q & (Nn - 1);             // source point
        const int var = q >> 12;                  // variant 0/1/2

        float2 ci = sC[i];
        const float x = ci.x, y = ci.y;
        float qx, qy;
        if (var == 0) {                           // (x, y+sy) - shift
            qx = x - 0.0005f;
            qy = (y + 0.001f) - 0.0005f;
        } else if (var == 1) {                    // (x+sx, y) - shift
            qx = (x + 0.001f) - 0.0005f;
            qy = y - 0.0005f;
        } else {                                  // (x+sx, y+sy) - shift
            qx = (x + 0.001f) - 0.0005f;
            qy = (y + 0.001f) - 0.0005f;
        }
        const float qq = qx * qx + qy * qy;       // contract(off): plain

        const int xlo = max(0, (int)floorf((qx - Rm) * (float)GD));
        const int xhi = min(GD - 1, (int)floorf((qx + Rm) * (float)GD));
        const int ylo = max(0, (int)floorf((qy - Rm) * (float)GD));
        const int yhi = min(GD - 1, (int)floorf((qy + Rm) * (float)GD));

        float bd = INFINITY;
        int   bi = 0x7fffffff;
        for (int cy = ylo; cy <= yhi; ++cy) {
            int cellLo = cy * GD + xlo;
            int cellHi = cy * GD + xhi;
            int s = (cellLo == 0) ? 0 : sCnt[cellLo - 1];
            int e = sCnt[cellHi];                 // contiguous row range
            for (int p = s; p < e; ++p) {
                int    jj = sSort[p];
                float2 c  = sC[jj];
                float  cc = c.x * c.x + c.y * c.y;
                float  qc = __builtin_fmaf(qy, c.y, qx * c.x);
                float  d2 = (qq + cc) - (qc + qc);
                if (d2 < bd || (d2 == bd && jj < bi)) { bd = d2; bi = jj; }
            }
        }
        sBi[tid] = bi;
    }
    __syncthreads();

    // ---------------- phase 5: gather + write, all 256 threads -------------
    // lane group cg=tid>>6 owns 16 channels; 64 lanes = 64 queries -> 256B
    // coalesced writes; gathers spread over 192 CUs (R5 had only 48).
    {
        const int ql = tid & 63;
        const int cg = tid >> 6;
        const int bi = sBi[ql];
        const int q0 = blockIdx.x * QPB;
        #pragma unroll
        for (int k = 0; k < 16; ++k) {
            int ch = cg * 16 + k;
            out[(size_t)ch * (4 * Nn) + Nn + q0 + ql] = values[ch * Nn + bi];
        }
    }
}

extern "C" void kernel_launch(void* const* d_in, const int* in_sizes, int n_in,
                              void* d_out, int out_size, void* d_ws, size_t ws_size,
                              hipStream_t stream) {
    const float* values = (const float*)d_in[0];  // [64, 4096] f32
    const float* coords = (const float*)d_in[1];  // [4096, 2] f32
    float* out = (float*)d_out;                   // [64, 16384] f32
    hipLaunchKernelGGL(upsample_fused_kernel, dim3(NBLK), dim3(256), 0, stream,
                       values, coords, out);
}